// Round 1
// baseline (45719.824 us; speedup 1.0000x reference)
//
#include <hip/hip_runtime.h>
#include <math.h>

#define T_STEPS 512
#define BATCH   64
#define HID     1024
#define G3      3072   // 3*HID

// ---------------------------------------------------------------------------
// GEMM: C[M][3072] = A[M][1024] @ W[3072][1024]^T + bias  (f32)
// 128x128 tile, K-tile 8, 256 threads, per-thread 2x2 fragments of 4x4.
// ---------------------------------------------------------------------------
__global__ __launch_bounds__(256) void gemm_gx_f32(
    const float* __restrict__ A, const float* __restrict__ W,
    const float* __restrict__ bias, float* __restrict__ C, int M)
{
    constexpr int K = 1024;
    __shared__ float As[8][132];
    __shared__ float Bs[8][132];
    const int tid = threadIdx.x;
    const int m0 = blockIdx.y * 128;
    const int n0 = blockIdx.x * 128;
    const int lr = tid >> 1;        // 0..127
    const int lc = (tid & 1) * 4;   // 0 or 4
    const float* Ap = A + (size_t)(m0 + lr) * K + lc;
    const float* Wp = W + (size_t)(n0 + lr) * K + lc;
    const int ty = tid >> 4;        // 0..15
    const int tx = tid & 15;        // 0..15

    float acc[2][2][4][4] = {};

    for (int k0 = 0; k0 < K; k0 += 8) {
        float4 av = *(const float4*)(Ap + k0);
        float4 wv = *(const float4*)(Wp + k0);
        __syncthreads();   // previous tile fully consumed
        As[lc + 0][lr] = av.x; As[lc + 1][lr] = av.y;
        As[lc + 2][lr] = av.z; As[lc + 3][lr] = av.w;
        Bs[lc + 0][lr] = wv.x; Bs[lc + 1][lr] = wv.y;
        Bs[lc + 2][lr] = wv.z; Bs[lc + 3][lr] = wv.w;
        __syncthreads();
        #pragma unroll
        for (int k = 0; k < 8; ++k) {
            float4 a0 = *(const float4*)&As[k][ty * 4];
            float4 a1 = *(const float4*)&As[k][64 + ty * 4];
            float4 b0 = *(const float4*)&Bs[k][tx * 4];
            float4 b1 = *(const float4*)&Bs[k][64 + tx * 4];
            float af[2][4] = {{a0.x, a0.y, a0.z, a0.w}, {a1.x, a1.y, a1.z, a1.w}};
            float bf[2][4] = {{b0.x, b0.y, b0.z, b0.w}, {b1.x, b1.y, b1.z, b1.w}};
            #pragma unroll
            for (int ia = 0; ia < 2; ++ia)
                #pragma unroll
                for (int jb = 0; jb < 2; ++jb)
                    #pragma unroll
                    for (int i = 0; i < 4; ++i)
                        #pragma unroll
                        for (int j = 0; j < 4; ++j)
                            acc[ia][jb][i][j] += af[ia][i] * bf[jb][j];
        }
    }

    #pragma unroll
    for (int ia = 0; ia < 2; ++ia) {
        #pragma unroll
        for (int jb = 0; jb < 2; ++jb) {
            const int col = n0 + jb * 64 + tx * 4;
            float4 bv = *(const float4*)&bias[col];
            #pragma unroll
            for (int i = 0; i < 4; ++i) {
                const int row = m0 + ia * 64 + ty * 4 + i;
                float4 o;
                o.x = acc[ia][jb][i][0] + bv.x;
                o.y = acc[ia][jb][i][1] + bv.y;
                o.z = acc[ia][jb][i][2] + bv.z;
                o.w = acc[ia][jb][i][3] + bv.w;
                *(float4*)&C[(size_t)row * G3 + col] = o;
            }
        }
    }
}

// ---------------------------------------------------------------------------
// One recurrent step.  256 blocks x 256 threads.
// Block owns hk0..hk0+3 (4 hidden cols) x 3 gates x all 64 batches.
// Waves partition K (ks = tid>>6); w_hh addresses are lane-uniform -> scalar
// loads; h tile staged in LDS as k-major float4 quads (even bank spread).
// ---------------------------------------------------------------------------
__global__ __launch_bounds__(256) void gru_step_f32(
    const float* __restrict__ gx_t,    // [64][3072]
    const float* __restrict__ h_prev,  // [64][1024]
    const float* __restrict__ w_hh,    // [3072][1024]
    const float* __restrict__ b_hh,    // [3072]
    float* __restrict__ y_t)           // [64][1024]  (= h_new)
{
    __shared__ float hs[16][256];      // [kq][b*4+ki] for one 64-k tile
    __shared__ float red[4][64][12];   // per-wave partials
    const int tid = threadIdx.x;
    const int hk0 = blockIdx.x * 4;
    const int b  = tid & 63;
    const int ks = tid >> 6;           // 0..3 (wave id)

    float acc[12] = {};                // [gate*4 + jr]

    for (int k0 = 0; k0 < HID; k0 += 64) {
        {   // stage h tile (transpose to k-major quads)
            const float* hp = h_prev + (size_t)b * HID + k0 + ks * 16;
            float4 v0 = *(const float4*)(hp + 0);
            float4 v1 = *(const float4*)(hp + 4);
            float4 v2 = *(const float4*)(hp + 8);
            float4 v3 = *(const float4*)(hp + 12);
            const int kq = ks * 4;
            *(float4*)&hs[kq + 0][b * 4] = v0;
            *(float4*)&hs[kq + 1][b * 4] = v1;
            *(float4*)&hs[kq + 2][b * 4] = v2;
            *(float4*)&hs[kq + 3][b * 4] = v3;
        }
        __syncthreads();
        #pragma unroll
        for (int qq = 0; qq < 4; ++qq) {
            const int kq = ks * 4 + qq;
            float4 hv = *(const float4*)&hs[kq][b * 4];
            const int kk = k0 + kq * 4;
            #pragma unroll
            for (int g = 0; g < 3; ++g) {
                #pragma unroll
                for (int jr = 0; jr < 4; ++jr) {
                    const float* wp = w_hh + ((size_t)(g * HID + hk0 + jr) << 10) + kk;
                    acc[g * 4 + jr] += hv.x * wp[0] + hv.y * wp[1]
                                     + hv.z * wp[2] + hv.w * wp[3];
                }
            }
        }
        __syncthreads();
    }

    #pragma unroll
    for (int i = 0; i < 12; ++i) red[ks][b][i] = acc[i];
    __syncthreads();

    {   // finalize: thread -> (b2, jw)
        const int b2 = tid & 63, jw = tid >> 6;
        const int hk = hk0 + jw;
        float sr = 0.f, sz = 0.f, sn = 0.f;
        #pragma unroll
        for (int s = 0; s < 4; ++s) {
            sr += red[s][b2][0 + jw];
            sz += red[s][b2][4 + jw];
            sn += red[s][b2][8 + jw];
        }
        const float gxr = gx_t[(size_t)b2 * G3 + hk];
        const float gxz = gx_t[(size_t)b2 * G3 + HID + hk];
        const float gxn = gx_t[(size_t)b2 * G3 + 2 * HID + hk];
        const float ghr = sr + b_hh[hk];
        const float ghz = sz + b_hh[HID + hk];
        const float ghn = sn + b_hh[2 * HID + hk];
        const float r = 1.f / (1.f + expf(-(gxr + ghr)));
        const float z = 1.f / (1.f + expf(-(gxz + ghz)));
        const float n = tanhf(gxn + r * ghn);
        const float hp = h_prev[(size_t)b2 * HID + hk];
        y_t[(size_t)b2 * HID + hk] = n + z * (hp - n);
    }
}

__global__ void copy_f32(const float* __restrict__ src, float* __restrict__ dst, int n)
{
    int i = blockIdx.x * blockDim.x + threadIdx.x;
    if (i < n) dst[i] = src[i];
}

// ---------------------------------------------------------------------------
extern "C" void kernel_launch(void* const* d_in, const int* in_sizes, int n_in,
                              void* d_out, int out_size, void* d_ws, size_t ws_size,
                              hipStream_t stream)
{
    const float* x    = (const float*)d_in[0];
    const float* h0   = (const float*)d_in[1];
    const float* wih0 = (const float*)d_in[2];
    const float* whh0 = (const float*)d_in[3];
    const float* bih0 = (const float*)d_in[4];
    const float* bhh0 = (const float*)d_in[5];
    const float* wih1 = (const float*)d_in[6];
    const float* whh1 = (const float*)d_in[7];
    const float* bih1 = (const float*)d_in[8];
    const float* bhh1 = (const float*)d_in[9];

    float* out = (float*)d_out;
    float* y   = out;                                  // [512][64][1024]
    float* hn  = out + (size_t)T_STEPS * BATCH * HID;  // [2][64][1024]
    float* gx  = (float*)d_ws;

    // largest T-chunk whose gx fits in workspace
    int TC = 512;
    while (TC > 2 && (size_t)TC * BATCH * G3 * 4 > ws_size) TC >>= 1;

    for (int layer = 0; layer < 2; ++layer) {
        const float* A_all = (layer == 0) ? x : y;
        const float* wih = layer ? wih1 : wih0;
        const float* whh = layer ? whh1 : whh0;
        const float* bih = layer ? bih1 : bih0;
        const float* bhh = layer ? bhh1 : bhh0;
        const float* hinit = h0 + (size_t)layer * BATCH * HID;

        for (int c0 = 0; c0 < T_STEPS; c0 += TC) {
            dim3 ggrid(G3 / 128, TC * BATCH / 128);
            gemm_gx_f32<<<ggrid, 256, 0, stream>>>(
                A_all + (size_t)c0 * BATCH * HID, wih, bih, gx, TC * BATCH);
            for (int t = c0; t < c0 + TC; ++t) {
                const float* hprev = (t == 0) ? hinit
                                              : (y + (size_t)(t - 1) * BATCH * HID);
                gru_step_f32<<<256, 256, 0, stream>>>(
                    gx + (size_t)(t - c0) * BATCH * G3, hprev, whh, bhh,
                    y + (size_t)t * BATCH * HID);
            }
        }
        copy_f32<<<(BATCH * HID + 255) / 256, 256, 0, stream>>>(
            y + (size_t)(T_STEPS - 1) * BATCH * HID,
            hn + (size_t)layer * BATCH * HID, BATCH * HID);
    }
}

// Round 2
// 13334.872 us; speedup vs baseline: 3.4286x; 3.4286x over previous
//
#include <hip/hip_runtime.h>
#include <hip/hip_bf16.h>
#include <math.h>

#define T_STEPS 512
#define BATCH   64
#define HID     1024
#define G3      3072

typedef __attribute__((ext_vector_type(8))) short          bf16x8;
typedef __attribute__((ext_vector_type(8))) unsigned short u16x8;
typedef __attribute__((ext_vector_type(4))) float          f32x4;

__device__ inline unsigned short f2bf(float f) {
    __hip_bfloat16 h = __float2bfloat16(f);   // RNE; compiler fuses pairs to v_cvt_pk_bf16_f32
    return *reinterpret_cast<unsigned short*>(&h);
}

// ---------------------------------------------------------------------------
// f32 -> bf16 bulk convert (weights, h0). n multiple of 4.
// ---------------------------------------------------------------------------
__global__ void cvt_f32_bf16(const float* __restrict__ src,
                             unsigned short* __restrict__ dst, int n)
{
    int i = (blockIdx.x * blockDim.x + threadIdx.x) * 4;
    if (i + 3 < n) {
        float4 v = *(const float4*)(src + i);
        ushort4 o;
        o.x = f2bf(v.x); o.y = f2bf(v.y); o.z = f2bf(v.z); o.w = f2bf(v.w);
        *(ushort4*)(dst + i) = o;
    }
}

// ---------------------------------------------------------------------------
// gx GEMM: C[M][3072] = A[M][1024](f32, cvt on the fly) @ Wbf[3072][1024]^T + b
// 128x128 tile, BK=64, 256 thr = 4 waves, each wave 64x64 out (4x4 MFMA frags)
// ---------------------------------------------------------------------------
__global__ __launch_bounds__(256) void gemm_gx_bf16(
    const float* __restrict__ A, const unsigned short* __restrict__ Wbf,
    const float* __restrict__ bias, float* __restrict__ C, int M)
{
    __shared__ unsigned short As[128][72];   // +8 pad: fragment reads 2-way max
    __shared__ unsigned short Bs[128][72];
    const int tid = threadIdx.x;
    const int l  = tid & 63;
    const int w  = tid >> 6;
    const int wm = w >> 1, wn = w & 1;
    const int m0 = blockIdx.y * 128, n0 = blockIdx.x * 128;
    const int lr = l & 15, lk = (l >> 4) * 8;

    f32x4 acc[4][4] = {};

    // staging assignments (coalesced: 16 consecutive lanes cover one row chunk)
    const int arow = tid >> 4, acol = (tid & 15) * 4;   // A: 8 reps x float4
    const int brow = tid >> 3, bcol = (tid & 7) * 8;    // B: 4 reps x 16B

    for (int k0 = 0; k0 < 1024; k0 += 64) {
        float4 av[8];
        #pragma unroll
        for (int r = 0; r < 8; ++r)
            av[r] = *(const float4*)(A + (size_t)(m0 + r * 16 + arow) * 1024 + k0 + acol);
        u16x8 bv[4];
        #pragma unroll
        for (int r = 0; r < 4; ++r)
            bv[r] = *(const u16x8*)(Wbf + (size_t)(n0 + r * 32 + brow) * 1024 + k0 + bcol);

        __syncthreads();   // previous iter's fragment reads complete
        #pragma unroll
        for (int r = 0; r < 8; ++r) {
            ushort4 o;
            o.x = f2bf(av[r].x); o.y = f2bf(av[r].y);
            o.z = f2bf(av[r].z); o.w = f2bf(av[r].w);
            *(ushort4*)&As[r * 16 + arow][acol] = o;
        }
        #pragma unroll
        for (int r = 0; r < 4; ++r)
            *(u16x8*)&Bs[r * 32 + brow][bcol] = bv[r];
        __syncthreads();

        #pragma unroll
        for (int kk = 0; kk < 2; ++kk) {
            bf16x8 af[4], bfr[4];
            #pragma unroll
            for (int i = 0; i < 4; ++i)
                af[i] = *(const bf16x8*)&As[wm * 64 + i * 16 + lr][kk * 32 + lk];
            #pragma unroll
            for (int j = 0; j < 4; ++j)
                bfr[j] = *(const bf16x8*)&Bs[wn * 64 + j * 16 + lr][kk * 32 + lk];
            #pragma unroll
            for (int i = 0; i < 4; ++i)
                #pragma unroll
                for (int j = 0; j < 4; ++j)
                    acc[i][j] = __builtin_amdgcn_mfma_f32_16x16x32_bf16(
                        af[i], bfr[j], acc[i][j], 0, 0, 0);
        }
    }

    #pragma unroll
    for (int j = 0; j < 4; ++j) {
        const int col = n0 + wn * 64 + j * 16 + lr;
        const float bv = bias[col];
        #pragma unroll
        for (int i = 0; i < 4; ++i) {
            const int rb = m0 + wm * 64 + i * 16 + (l >> 4) * 4;
            #pragma unroll
            for (int r = 0; r < 4; ++r)
                C[(size_t)(rb + r) * G3 + col] = acc[i][j][r] + bv;
        }
    }
}

// ---------------------------------------------------------------------------
// One recurrent step, pure-register MFMA. grid (64,4), block = 64 (1 wave).
// Block owns 16 hidden cols (x3 gates) x 16 batches. No LDS, no barriers.
// ---------------------------------------------------------------------------
__global__ __launch_bounds__(64) void gru_step_mfma(
    const float* __restrict__ gx_t,           // [64][3072]
    const unsigned short* __restrict__ hbf,   // [64][1024] bf16 (prev h)
    const float* __restrict__ hprev,          // [64][1024] f32  (prev h exact)
    const unsigned short* __restrict__ whh,   // [3072][1024] bf16
    const float* __restrict__ bhh,            // [3072]
    float* __restrict__ y_t,                  // [64][1024]
    unsigned short* __restrict__ hbf_out)     // [64][1024]
{
    const int l  = threadIdx.x;
    const int j0 = blockIdx.x * 16;
    const int by = blockIdx.y;                // batch group (16)
    const int lr = l & 15, lk = (l >> 4) * 8;

    f32x4 ar = {0.f, 0.f, 0.f, 0.f};
    f32x4 az = {0.f, 0.f, 0.f, 0.f};
    f32x4 an = {0.f, 0.f, 0.f, 0.f};

    const unsigned short* hp = hbf + (size_t)(by * 16 + lr) * HID + lk;
    const unsigned short* wr = whh + (size_t)(j0 + lr) * HID + lk;
    const unsigned short* wz = wr + (size_t)HID * HID;
    const unsigned short* wn = wz + (size_t)HID * HID;

    #pragma unroll 4
    for (int k = 0; k < HID; k += 32) {
        bf16x8 a  = *(const bf16x8*)(hp + k);
        bf16x8 br = *(const bf16x8*)(wr + k);
        bf16x8 bz = *(const bf16x8*)(wz + k);
        bf16x8 bn = *(const bf16x8*)(wn + k);
        ar = __builtin_amdgcn_mfma_f32_16x16x32_bf16(a, br, ar, 0, 0, 0);
        az = __builtin_amdgcn_mfma_f32_16x16x32_bf16(a, bz, az, 0, 0, 0);
        an = __builtin_amdgcn_mfma_f32_16x16x32_bf16(a, bn, an, 0, 0, 0);
    }

    const int jc = j0 + lr;
    const float br_ = bhh[jc], bz_ = bhh[HID + jc], bn_ = bhh[2 * HID + jc];
    #pragma unroll
    for (int r = 0; r < 4; ++r) {
        const int b = by * 16 + (l >> 4) * 4 + r;   // C/D row = 4*(l>>4)+reg
        const float gxr = gx_t[(size_t)b * G3 + jc];
        const float gxz = gx_t[(size_t)b * G3 + HID + jc];
        const float gxn = gx_t[(size_t)b * G3 + 2 * HID + jc];
        const float rr = 1.f / (1.f + __expf(-(gxr + ar[r] + br_)));
        const float zz = 1.f / (1.f + __expf(-(gxz + az[r] + bz_)));
        const float nn = tanhf(gxn + rr * (an[r] + bn_));
        const float hpv = hprev[(size_t)b * HID + jc];
        const float hnv = nn + zz * (hpv - nn);
        y_t[(size_t)b * HID + jc] = hnv;
        hbf_out[(size_t)b * HID + jc] = f2bf(hnv);
    }
}

__global__ void copy_f32(const float* __restrict__ src, float* __restrict__ dst, int n)
{
    int i = blockIdx.x * blockDim.x + threadIdx.x;
    if (i < n) dst[i] = src[i];
}

// ---------------------------------------------------------------------------
extern "C" void kernel_launch(void* const* d_in, const int* in_sizes, int n_in,
                              void* d_out, int out_size, void* d_ws, size_t ws_size,
                              hipStream_t stream)
{
    const float* x    = (const float*)d_in[0];
    const float* h0   = (const float*)d_in[1];
    const float* wih[2] = {(const float*)d_in[2], (const float*)d_in[6]};
    const float* whh[2] = {(const float*)d_in[3], (const float*)d_in[7]};
    const float* bih[2] = {(const float*)d_in[4], (const float*)d_in[8]};
    const float* bhh[2] = {(const float*)d_in[5], (const float*)d_in[9]};

    float* out = (float*)d_out;
    float* y   = out;                                  // [512][64][1024]
    float* hn  = out + (size_t)T_STEPS * BATCH * HID;  // [2][64][1024]

    const size_t WSZ = (size_t)G3 * HID;               // 3145728 elems
    unsigned short* wsu = (unsigned short*)d_ws;
    unsigned short* whh_bf[2] = {wsu, wsu + WSZ};
    unsigned short* wih_bf[2] = {wsu + 2 * WSZ, wsu + 3 * WSZ};
    unsigned short* hbf = wsu + 4 * WSZ;               // 2 x 65536 (ping-pong)
    float* gx = (float*)(wsu + 4 * WSZ + 2 * (size_t)BATCH * HID);
    const size_t fixed_bytes = (4 * WSZ + 2 * (size_t)BATCH * HID) * 2;
    const size_t gx_bytes = ws_size > fixed_bytes ? ws_size - fixed_bytes : 0;

    int TC = 512;   // T-chunk whose f32 gx fits in remaining workspace
    while (TC > 2 && (size_t)TC * BATCH * G3 * 4 > gx_bytes) TC >>= 1;

    // pre-convert weights to bf16
    for (int layer = 0; layer < 2; ++layer) {
        cvt_f32_bf16<<<(int)(WSZ / 1024), 256, 0, stream>>>(whh[layer], whh_bf[layer], (int)WSZ);
        cvt_f32_bf16<<<(int)(WSZ / 1024), 256, 0, stream>>>(wih[layer], wih_bf[layer], (int)WSZ);
    }

    for (int layer = 0; layer < 2; ++layer) {
        const float* A_all = (layer == 0) ? x : y;
        const float* hinit = h0 + (size_t)layer * BATCH * HID;

        cvt_f32_bf16<<<BATCH * HID / 1024, 256, 0, stream>>>(hinit, hbf, BATCH * HID);

        for (int c0 = 0; c0 < T_STEPS; c0 += TC) {
            dim3 ggrid(G3 / 128, TC * BATCH / 128);
            gemm_gx_bf16<<<ggrid, 256, 0, stream>>>(
                A_all + (size_t)c0 * BATCH * HID, wih_bf[layer], bih[layer],
                gx, TC * BATCH);
            for (int t = c0; t < c0 + TC; ++t) {
                const float* hprev = (t == 0) ? hinit
                                              : (y + (size_t)(t - 1) * BATCH * HID);
                gru_step_mfma<<<dim3(64, 4), 64, 0, stream>>>(
                    gx + (size_t)(t - c0) * BATCH * G3,
                    hbf + (size_t)(t & 1) * BATCH * HID,
                    hprev, whh_bf[layer], bhh[layer],
                    y + (size_t)t * BATCH * HID,
                    hbf + (size_t)((t + 1) & 1) * BATCH * HID);
            }
        }
        copy_f32<<<(BATCH * HID + 255) / 256, 256, 0, stream>>>(
            y + (size_t)(T_STEPS - 1) * BATCH * HID,
            hn + (size_t)layer * BATCH * HID, BATCH * HID);
    }
}